// Round 3
// baseline (137.563 us; speedup 1.0000x reference)
//
#include <hip/hip_runtime.h>

#define FDIM 256
#define NSAMP 10
#define NEGF -9.0e15f

// Evidence-pinned dtypes (prior session): features fp32, out fp32,
// index width auto-detected per-wave via odd-word ballot.
//
// V4: best-of-V1/V3 + segmented reduce.
//  - 1 wave/node, float4 lanes, all 10 embed rows in flight (V1 MLP),
//    no LDS / no barriers / no duplicate self-row (V3's costs removed).
//  - 10 dot-reductions in 13 shuffles (segmented split-tree) + 1 realign,
//    then lane-parallel softmax: 56 DS-ops/wave vs V1's 80 / V3's 57,
//    at half V3's wave count -> 51% fewer total DS ops.
//  - index width candidates (int32/int64) preloaded in parallel with the
//    ballot word: 3 serial VMEM rounds (nidx -> uid -> embed), the minimum.
// Dedupe/masking exactness: a duplicate column's raw score equals its valid
// twin's score (same uid), so un-masked max == valid max; duplicate weights
// are zeroed before the sum butterfly.

__global__ __launch_bounds__(256, 4) void AttentionAggregator_42477226557515_kernel(
    const float* __restrict__ features,   // [VOCAB, FDIM] fp32
    const int* __restrict__ nodes_w,      // [N] int32/int64 word view
    const int* __restrict__ uids_w,       // [M]
    const int* __restrict__ nidx_w,       // [N, NSAMP]
    float* __restrict__ out,              // [N, FDIM] fp32
    int n_nodes)
{
    const int lane = threadIdx.x & 63;
    const int n = (blockIdx.x << 2) + (threadIdx.x >> 6);   // 4 waves/block, 1 node/wave
    if (n >= n_nodes) return;             // wave-uniform; no barriers below

    // ---- round 1 (all independent, in flight together) ----
    const int bw    = nodes_w[2 * lane + 1];   // ballot word for width detect
    const int nid32 = nodes_w[n];              // int32 candidate
    const int nid64 = nodes_w[2 * n];          // int64 candidate (low word)
    int c32 = 0, c64 = 0;
    if (lane < NSAMP) {
        const int j = n * NSAMP + lane;
        c32 = nidx_w[j];
        c64 = nidx_w[2 * j];
    }
    const unsigned long long oddnz = __ballot(bw != 0);
    const bool i64 = (oddnz == 0ULL);          // int64 positive ids -> odd words all zero
    const int node_id = i64 ? nid64 : nid32;
    const int c_own   = i64 ? c64 : c32;

    const int off = lane << 2;                 // 4 fp32 per lane = 16B vector

    // ---- round 2: self row + own uid ----
    const float4 srv = *(const float4*)(features + (size_t)node_id * FDIM + off);
    int u_own = 0;
    if (lane < NSAMP)
        u_own = i64 ? uids_w[2 * c_own] : uids_w[c_own];

    // lane-parallel dedupe: lane s invalid if some t<s has the same column
    // (overlaps with round-2 loads; mask .set(1.0) is idempotent per column)
    bool vown = true;
#pragma unroll
    for (int t = 0; t < NSAMP; ++t) {
        const int ct = __shfl(c_own, t, 64);
        if (t < lane && ct == c_own) vown = false;
    }

    // ---- round 3: all 10 embed rows in flight ----
    float4 e[NSAMP];
#pragma unroll
    for (int s = 0; s < NSAMP; ++s) {
        const int u = __shfl(u_own, s, 64);
        e[s] = *(const float4*)(features + (size_t)u * FDIM + off);
    }

    // per-lane partial dots (4 features each)
    float ps[NSAMP];
#pragma unroll
    for (int s = 0; s < NSAMP; ++s)
        ps[s] = srv.x * e[s].x + srv.y * e[s].y + srv.z * e[s].z + srv.w * e[s].w;

    // ---- segmented multi-value reduce: 10 sums over 64 lanes in 13 shuffles ----
    const int b32 = (lane >> 5) & 1, b16 = (lane >> 4) & 1;
    const int b8  = (lane >> 3) & 1, b4  = (lane >> 2) & 1;

    // L1 (d=32): split 10 -> 5; b32=0 keeps scores 0..4, b32=1 keeps 5..9
    float q[5];
#pragma unroll
    for (int i = 0; i < 5; ++i) {
        const float keep = b32 ? ps[i + 5] : ps[i];
        const float send = b32 ? ps[i] : ps[i + 5];
        q[i] = keep + __shfl_xor(send, 32, 64);
    }
    // L2 (d=16): split 5 -> {0,1|3,4} + dup q[2]
    float r0, r1, r2;
    { const float k = b16 ? q[3] : q[0], s_ = b16 ? q[0] : q[3]; r0 = k + __shfl_xor(s_, 16, 64); }
    { const float k = b16 ? q[4] : q[1], s_ = b16 ? q[1] : q[4]; r1 = k + __shfl_xor(s_, 16, 64); }
    r2 = q[2] + __shfl_xor(q[2], 16, 64);
    // L3 (d=8): split {r0|r1} + dup r2
    float s0, s1;
    { const float k = b8 ? r1 : r0, s_ = b8 ? r0 : r1; s0 = k + __shfl_xor(s_, 8, 64); }
    s1 = r2 + __shfl_xor(r2, 8, 64);
    // L4 (d=4): split {s0|s1}
    float t0;
    { const float k = b4 ? s1 : s0, s_ = b4 ? s0 : s1; t0 = k + __shfl_xor(s_, 4, 64); }
    // L5, L6: plain butterfly on the single remaining value
    t0 += __shfl_xor(t0, 2, 64);
    t0 += __shfl_xor(t0, 1, 64);
    // t0 = full sum of score: b4 ? 5*b32+2 : 5*b32 + 3*b16 + b8

    // realign: lane s (s<10) fetches score s from its canonical source lane
    int src;
    {
        const int bb32 = (lane >= 5) ? 1 : 0;
        const int rr   = lane - 5 * bb32;
        if (rr == 2) src = 4 + 32 * bb32;
        else {
            const int bb16 = (rr >= 3) ? 1 : 0;
            const int bb8  = rr - 3 * bb16;
            src = 8 * bb8 + 16 * bb16 + 32 * bb32;
        }
    }
    const float sc_raw = __shfl(t0, src & 63, 64);
    const float sc_own = (lane < NSAMP) ? sc_raw : NEGF;

    // lane-parallel softmax (dup scores == their valid twins, so max is exact;
    // dup/invalid weights zeroed before the sum)
    float m = sc_own;
#pragma unroll
    for (int d = 32; d > 0; d >>= 1) m = fmaxf(m, __shfl_xor(m, d, 64));
    float w_own = (lane < NSAMP && vown) ? __expf(sc_own - m) : 0.0f;
    float l = w_own;
#pragma unroll
    for (int d = 32; d > 0; d >>= 1) l += __shfl_xor(l, d, 64);
    const float inv = 1.0f / l;

    // weighted sum over the 10 embed rows (still in registers)
    float a0 = 0.f, a1 = 0.f, a2 = 0.f, a3 = 0.f;
#pragma unroll
    for (int s = 0; s < NSAMP; ++s) {
        const float ws = __shfl(w_own, s, 64);
        a0 += ws * e[s].x;
        a1 += ws * e[s].y;
        a2 += ws * e[s].z;
        a3 += ws * e[s].w;
    }

    float4 o;
    o.x = a0 * inv; o.y = a1 * inv; o.z = a2 * inv; o.w = a3 * inv;
    *(float4*)(out + (size_t)n * FDIM + off) = o;
}

extern "C" void kernel_launch(void* const* d_in, const int* in_sizes, int n_in,
                              void* d_out, int out_size, void* d_ws, size_t ws_size,
                              hipStream_t stream) {
    const float* features = (const float*)d_in[0];
    const int* nodes      = (const int*)d_in[1];
    const int* uids       = (const int*)d_in[2];
    const int* nidx       = (const int*)d_in[3];
    float* out            = (float*)d_out;

    const int n_nodes = out_size / FDIM;          // 4096, dtype-proof
    const int blocks  = (n_nodes + 3) / 4;        // 4 nodes (waves) per 256-thread block

    hipLaunchKernelGGL(AttentionAggregator_42477226557515_kernel,
                       dim3(blocks), dim3(256), 0, stream,
                       features, nodes, uids, nidx, out, n_nodes);
}